// Round 3
// baseline (714.568 us; speedup 1.0000x reference)
//
#include <hip/hip_runtime.h>
#include <hip/hip_bf16.h>

typedef __bf16 bf16x8 __attribute__((ext_vector_type(8)));
typedef short s16x4 __attribute__((ext_vector_type(4)));
typedef float f32x4 __attribute__((ext_vector_type(4)));
typedef unsigned int u32;

#define SW1_K 216   // 192 W1 + col192=b1 + 193..207 zero + pad->216 (mult of 8)
#define SW2_K 152   // 128 W2 + col128=b2 + 129..143 zero + pad->152

static __device__ __forceinline__ f32x4 mfma16(s16x4 a, s16x4 b, f32x4 c) {
#if __has_builtin(__builtin_amdgcn_mfma_f32_16x16x16bf16_1k)
    return __builtin_amdgcn_mfma_f32_16x16x16bf16_1k(a, b, c, 0, 0, 0);
#elif __has_builtin(__builtin_amdgcn_mfma_f32_16x16x16_bf16)
    typedef __bf16 bf16x4_t __attribute__((ext_vector_type(4)));
    return __builtin_amdgcn_mfma_f32_16x16x16_bf16(
        __builtin_bit_cast(bf16x4_t, a), __builtin_bit_cast(bf16x4_t, b), c, 0, 0, 0);
#else
    asm volatile("s_nop 1\n\tv_mfma_f32_16x16x16_bf16 %0, %1, %2, %0\n\ts_nop 7\n\ts_nop 7"
                 : "+v"(c) : "v"(a), "v"(b));
    return c;
#endif
}

// softplus on two f32, packed to a bf16 pair
static __device__ __forceinline__ u32 packsp(float x0, float x1) {
    float s0 = fmaxf(x0, 0.f) + __logf(1.f + __expf(-fabsf(x0)));
    float s1 = fmaxf(x1, 0.f) + __logf(1.f + __expf(-fabsf(x1)));
    __bf16 b0 = (__bf16)s0, b1 = (__bf16)s1;
    union { unsigned short s[2]; u32 w; } u;
    u.s[0] = __builtin_bit_cast(unsigned short, b0);
    u.s[1] = __builtin_bit_cast(unsigned short, b1);
    return u.w;
}

static __device__ __forceinline__ s16x4 mk4(u32 lo, u32 hi) {
    union { u32 w[2]; s16x4 v; } u;
    u.w[0] = lo; u.w[1] = hi;
    return u.v;
}

// D=64, R=64, H=128, K1=192. hid^T = W1^T*edge^T (16x16x32), out^T = W2^T*hid^T (16x16x16).
__global__ __launch_bounds__(512, 4) void edge_mlp_kernel(
    const float* __restrict__ node_feats,   // [N,64]
    const float* __restrict__ edge_feats,   // [E,64]
    const int* __restrict__ src_idx,        // [E]
    const int* __restrict__ dst_idx,        // [E]
    const float* __restrict__ W1,           // [192,128]
    const float* __restrict__ b1,           // [128]
    const float* __restrict__ W2,           // [128,64]
    const float* __restrict__ b2,           // [64]
    float* __restrict__ out,                // [E,64]
    int E, int nchunks)
{
    __shared__ alignas(16) __bf16 sW1[128 * SW1_K];  // 55296 B, W1^T: [h][k]
    __shared__ alignas(16) __bf16 sW2[64 * SW2_K];   // 19456 B, W2^T: [r][h]

    const int tid  = threadIdx.x;
    const int lane = tid & 63;
    const int wid  = tid >> 6;

    // ---- stage W1^T (+b1 at col 192, zeros 193..207), W2^T (+b2 at 128, zeros 129..143) ----
    for (int i = tid; i < 192 * 128; i += 512) {
        int k = i >> 7, h = i & 127;
        sW1[h * SW1_K + k] = (__bf16)W1[i];
    }
    for (int i = tid; i < 128 * 32; i += 512) {
        int h = i >> 5, cc = 192 + (i & 31);
        if (cc < 208) sW1[h * SW1_K + cc] = (cc == 192) ? (__bf16)b1[h] : (__bf16)0.f;
    }
    for (int i = tid; i < 128 * 64; i += 512) {
        int k = i >> 6, r = i & 63;
        sW2[r * SW2_K + k] = (__bf16)W2[i];
    }
    for (int i = tid; i < 64 * 32; i += 512) {
        int r = i >> 5, cc = 128 + (i & 31);
        if (cc < 144) sW2[r * SW2_K + cc] = (cc == 128) ? (__bf16)b2[r] : (__bf16)0.f;
    }
    __syncthreads();

    const int q   = lane >> 4;     // 0..3
    const int r16 = lane & 15;     // 0..15
    const int ko  = q * 8;         // x32 k-offset
    const int k4  = q * 4;         // x16 k-offset

    const s16x4 one = {(short)(q == 0 ? 0x3F80 : 0), 0, 0, 0};  // B-frag of the constant-1 row

    int c = blockIdx.x;
    int is0, id0, is1, id1, ie0, ie1;
    {
        int b = c * 256 + wid * 32;
        int e0 = b + r16, e1 = b + 16 + r16;
        ie0 = e0 < E ? e0 : E - 1;
        ie1 = e1 < E ? e1 : E - 1;
        is0 = src_idx[ie0]; id0 = dst_idx[ie0];
        is1 = src_idx[ie1]; id1 = dst_idx[ie1];
    }

    while (c < nchunks) {
        const int base = c * 256 + wid * 32;
        const float* s0p = node_feats + (size_t)is0 * 64;
        const float* d0p = node_feats + (size_t)id0 * 64;
        const float* e0p = edge_feats + (size_t)ie0 * 64;
        const float* s1p = node_feats + (size_t)is1 * 64;
        const float* d1p = node_feats + (size_t)id1 * 64;
        const float* e1p = edge_feats + (size_t)ie1 * 64;

        // prefetch next chunk's indices under this chunk's compute
        const int cn = c + gridDim.x;
        int nis0 = is0, nid0 = id0, nis1 = is1, nid1 = id1, nie0 = ie0, nie1 = ie1;
        if (cn < nchunks) {
            int bb = cn * 256 + wid * 32;
            int e0 = bb + r16, e1 = bb + 16 + r16;
            nie0 = e0 < E ? e0 : E - 1;
            nie1 = e1 < E ? e1 : E - 1;
            nis0 = src_idx[nie0]; nid0 = dst_idx[nie0];
            nis1 = src_idx[nie1]; nid1 = dst_idx[nie1];
        }

        f32x4 acc1[2][8];
#pragma unroll
        for (int m = 0; m < 2; ++m)
#pragma unroll
            for (int n = 0; n < 8; ++n) acc1[m][n] = (f32x4){0.f, 0.f, 0.f, 0.f};

        // ---- GEMM1: hid^T[128][16] = W1^T . edge^T, K-steps of 32, streaming t ----
#pragma unroll
        for (int t = 0; t < 6; ++t) {
            const float* a0 = (t < 2 ? s0p + t * 32 : t < 4 ? d0p + (t - 2) * 32 : e0p + (t - 4) * 32) + ko;
            const float* a1 = (t < 2 ? s1p + t * 32 : t < 4 ? d1p + (t - 2) * 32 : e1p + (t - 4) * 32) + ko;
            f32x4 g00 = *(const f32x4*)a0;
            f32x4 g01 = *(const f32x4*)(a0 + 4);
            f32x4 g10 = *(const f32x4*)a1;
            f32x4 g11 = *(const f32x4*)(a1 + 4);
            bf16x8 ef0, ef1;
#pragma unroll
            for (int j = 0; j < 4; ++j) {
                ef0[j] = (__bf16)g00[j]; ef0[j + 4] = (__bf16)g01[j];
                ef1[j] = (__bf16)g10[j]; ef1[j + 4] = (__bf16)g11[j];
            }
#pragma unroll
            for (int n = 0; n < 8; ++n) {
                bf16x8 w1f = *(const bf16x8*)&sW1[(n * 16 + r16) * SW1_K + t * 32 + ko];
                acc1[0][n] = __builtin_amdgcn_mfma_f32_16x16x32_bf16(w1f, ef0, acc1[0][n], 0, 0, 0);
                acc1[1][n] = __builtin_amdgcn_mfma_f32_16x16x32_bf16(w1f, ef1, acc1[1][n], 0, 0, 0);
            }
        }
        // bias1 as one 16-wide K-step (A = sW1 cols 192..207, B = unit)
#pragma unroll
        for (int n = 0; n < 8; ++n) {
            s16x4 wb = *(const s16x4*)&sW1[(n * 16 + r16) * SW1_K + 192 + k4];
            acc1[0][n] = mfma16(wb, one, acc1[0][n]);
            acc1[1][n] = mfma16(wb, one, acc1[1][n]);
        }

        // ---- softplus + pack: lane(q,r16) holds hid[e=r16][h=16n+4q+i] -> bf16 pairs ----
        u32 P0[8][2], P1[8][2];
#pragma unroll
        for (int n = 0; n < 8; ++n) {
            P0[n][0] = packsp(acc1[0][n][0], acc1[0][n][1]);
            P0[n][1] = packsp(acc1[0][n][2], acc1[0][n][3]);
            P1[n][0] = packsp(acc1[1][n][0], acc1[1][n][1]);
            P1[n][1] = packsp(acc1[1][n][2], acc1[1][n][3]);
        }

        // ---- GEMM2: out^T[64][16] = W2^T . hid^T, 16x16x16, A2-frags straight from P ----
        f32x4 acc2[2][4];
#pragma unroll
        for (int m = 0; m < 2; ++m)
#pragma unroll
            for (int rt = 0; rt < 4; ++rt) acc2[m][rt] = (f32x4){0.f, 0.f, 0.f, 0.f};

        __builtin_amdgcn_s_setprio(1);
#pragma unroll
        for (int n = 0; n < 8; ++n) {
            s16x4 p0 = mk4(P0[n][0], P0[n][1]);
            s16x4 p1 = mk4(P1[n][0], P1[n][1]);
#pragma unroll
            for (int rt = 0; rt < 4; ++rt) {
                s16x4 w2f = *(const s16x4*)&sW2[(rt * 16 + r16) * SW2_K + n * 16 + k4];
                acc2[0][rt] = mfma16(w2f, p0, acc2[0][rt]);
                acc2[1][rt] = mfma16(w2f, p1, acc2[1][rt]);
            }
        }
        // bias2 as one 16-wide K-step
#pragma unroll
        for (int rt = 0; rt < 4; ++rt) {
            s16x4 wb2 = *(const s16x4*)&sW2[(rt * 16 + r16) * SW2_K + 128 + k4];
            acc2[0][rt] = mfma16(wb2, one, acc2[0][rt]);
            acc2[1][rt] = mfma16(wb2, one, acc2[1][rt]);
        }
        __builtin_amdgcn_s_setprio(0);

        // ---- epilogue: lane(q,r16) holds out[e][16rt+4q+i] -> dwordx4 stores ----
        {
            int e0 = base + r16;
            if (e0 < E) {
                float* op = out + (size_t)e0 * 64 + k4;
#pragma unroll
                for (int rt = 0; rt < 4; ++rt)
                    *(f32x4*)(op + rt * 16) = acc2[0][rt];
            }
            int e1 = base + 16 + r16;
            if (e1 < E) {
                float* op = out + (size_t)e1 * 64 + k4;
#pragma unroll
                for (int rt = 0; rt < 4; ++rt)
                    *(f32x4*)(op + rt * 16) = acc2[1][rt];
            }
        }

        is0 = nis0; id0 = nid0; is1 = nis1; id1 = nid1; ie0 = nie0; ie1 = nie1;
        c = cn;
    }
}

extern "C" void kernel_launch(void* const* d_in, const int* in_sizes, int n_in,
                              void* d_out, int out_size, void* d_ws, size_t ws_size,
                              hipStream_t stream) {
    const float* node_feats = (const float*)d_in[0];
    const float* edge_feats = (const float*)d_in[1];
    const int*   src_idx    = (const int*)d_in[2];
    const int*   dst_idx    = (const int*)d_in[3];
    const float* W1         = (const float*)d_in[4];
    const float* b1         = (const float*)d_in[5];
    const float* W2         = (const float*)d_in[6];
    const float* b2         = (const float*)d_in[7];
    float* out = (float*)d_out;

    const int E = in_sizes[2];
    const int nchunks = (E + 255) / 256;
    int grid = nchunks < 512 ? nchunks : 512;

    edge_mlp_kernel<<<grid, 512, 0, stream>>>(node_feats, edge_feats, src_idx, dst_idx,
                                              W1, b1, W2, b2, out, E, nchunks);
}

// Round 5
// 180.482 us; speedup vs baseline: 3.9592x; 3.9592x over previous
//
#include <hip/hip_runtime.h>
#include <hip/hip_bf16.h>

typedef __bf16 bf16x8 __attribute__((ext_vector_type(8)));
typedef __bf16 bf16x4_t __attribute__((ext_vector_type(4)));
typedef short s16x4 __attribute__((ext_vector_type(4)));
typedef float f32x4 __attribute__((ext_vector_type(4)));
typedef unsigned int u32;

static __device__ __forceinline__ f32x4 mfma32(bf16x8 a, bf16x8 b, f32x4 c) {
    return __builtin_amdgcn_mfma_f32_16x16x32_bf16(a, b, c, 0, 0, 0);
}

static __device__ __forceinline__ f32x4 mfma16(s16x4 a, s16x4 b, f32x4 c) {
#if __has_builtin(__builtin_amdgcn_mfma_f32_16x16x16bf16_1k)
    return __builtin_amdgcn_mfma_f32_16x16x16bf16_1k(a, b, c, 0, 0, 0);
#elif __has_builtin(__builtin_amdgcn_mfma_f32_16x16x16_bf16)
    return __builtin_amdgcn_mfma_f32_16x16x16_bf16(
        __builtin_bit_cast(bf16x4_t, a), __builtin_bit_cast(bf16x4_t, b), c, 0, 0, 0);
#else
    asm volatile("s_nop 1\n\tv_mfma_f32_16x16x16_bf16 %0, %1, %2, %0\n\ts_nop 7\n\ts_nop 7"
                 : "+v"(c) : "v"(a), "v"(b));
    return c;
#endif
}

// numerically-stable softplus on two f32, packed to a bf16 pair
static __device__ __forceinline__ u32 packsp(float x0, float x1) {
    float s0 = fmaxf(x0, 0.f) + __logf(1.f + __expf(-fabsf(x0)));
    float s1 = fmaxf(x1, 0.f) + __logf(1.f + __expf(-fabsf(x1)));
    union { __bf16 b[2]; u32 w; } u;
    u.b[0] = (__bf16)s0; u.b[1] = (__bf16)s1;
    return u.w;
}

static __device__ __forceinline__ s16x4 mk4(u32 lo, u32 hi) {
    union { u32 w[2]; s16x4 v; } u;
    u.w[0] = lo; u.w[1] = hi;
    return u.v;
}

// D=64, R=64, H=128, K1=192. hid^T = W1^T*edge^T (16x16x32); out^T = W2^T*hid^T (16x16x16).
// Pre-swizzled LDS frag layouts: frag(X) = 16B at lane*16 + imm -> conflict-free ds_read_b128.
__global__ __launch_bounds__(512, 4) void edge_mlp_kernel(
    const float* __restrict__ node_feats,   // [N,64]
    const float* __restrict__ edge_feats,   // [E,64]
    const int* __restrict__ src_idx,        // [E]
    const int* __restrict__ dst_idx,        // [E]
    const float* __restrict__ W1,           // [192,128]
    const float* __restrict__ b1,           // [128]
    const float* __restrict__ W2,           // [128,64]
    const float* __restrict__ b2,           // [64]
    float* __restrict__ out,                // [E,64]
    int E, int nchunks)
{
    // A-frag(n,t) of GEMM1: lane(q,r16) holds W1^T[h=n*16+r16][k=t*32+q*8+j], j=0..7
    __shared__ alignas(16) __bf16 sW1f[8 * 6 * 64 * 8];   // 49152 B
    // A-frag-pair(rt,np) of GEMM2: 8B n=2np frag + 8B n=2np+1 frag per lane
    __shared__ alignas(16) __bf16 sW2f[4 * 4 * 64 * 8];   // 16384 B
    __shared__ alignas(16) __bf16 sB1f[8 * 64 * 4];       // 4096 B
    __shared__ alignas(16) __bf16 sB2f[4 * 64 * 4];       // 2048 B  (total 71680)

    const int tid  = threadIdx.x;
    const int lane = tid & 63;
    const int wid  = tid >> 6;

    // ---- stage pre-swizzled fragments (once per persistent block) ----
    for (int i = tid; i < 192 * 128; i += 512) {
        int k = i >> 7, h = i & 127;
        int n = h >> 4, r = h & 15, t = k >> 5, kq = (k >> 3) & 3, j = k & 7;
        sW1f[((n * 6 + t) * 64 + kq * 16 + r) * 8 + j] = (__bf16)W1[i];
    }
    for (int i = tid; i < 128 * 64; i += 512) {
        int h = i >> 6, r = i & 63;
        int rt = r >> 4, r16 = r & 15, n = h >> 4, hq = (h >> 2) & 3, j = h & 3;
        sW2f[((rt * 4 + (n >> 1)) * 64 + hq * 16 + r16) * 8 + (n & 1) * 4 + j] = (__bf16)W2[i];
    }
    for (int s = tid; s < 8 * 64 * 4; s += 512) {
        int j = s & 3, ln = (s >> 2) & 63, n = s >> 8;
        sB1f[s] = (j == 0 && ln < 16) ? (__bf16)b1[n * 16 + ln] : (__bf16)0.f;
    }
    for (int s = tid; s < 4 * 64 * 4; s += 512) {
        int j = s & 3, ln = (s >> 2) & 63, rt = s >> 8;
        sB2f[s] = (j == 0 && ln < 16) ? (__bf16)b2[rt * 16 + ln] : (__bf16)0.f;
    }
    __syncthreads();

    const int q   = lane >> 4;
    const int r16 = lane & 15;
    const int ko  = q * 8;

    const __bf16* w1p = &sW1f[lane * 8];
    const __bf16* w2p = &sW2f[lane * 8];
    const __bf16* b1p = &sB1f[lane * 4];
    const __bf16* b2p = &sB2f[lane * 4];

    const s16x4 one = {(short)(q == 0 ? 0x3F80 : 0), 0, 0, 0};

    int c = blockIdx.x;
    u32 os0, od0, oe0, os1, od1, oe1;   // gather offsets (elements), ko folded in
    {
        int b = c * 256 + wid * 32;
        int e0 = b + r16, e1 = b + 16 + r16;
        int ie0 = e0 < E ? e0 : E - 1;
        int ie1 = e1 < E ? e1 : E - 1;
        os0 = (u32)src_idx[ie0] * 64 + ko; od0 = (u32)dst_idx[ie0] * 64 + ko;
        os1 = (u32)src_idx[ie1] * 64 + ko; od1 = (u32)dst_idx[ie1] * 64 + ko;
        oe0 = (u32)ie0 * 64 + ko;          oe1 = (u32)ie1 * 64 + ko;
    }

#define LOAD_T(T, B) {                                                          \
        u32 oo0 = (T < 2) ? os0 + T * 32 : (T < 4) ? od0 + (T - 2) * 32 : oe0 + (T - 4) * 32; \
        u32 oo1 = (T < 2) ? os1 + T * 32 : (T < 4) ? od1 + (T - 2) * 32 : oe1 + (T - 4) * 32; \
        const float* bp = (T < 4) ? node_feats : edge_feats;                    \
        B[0] = *(const f32x4*)(bp + oo0); B[1] = *(const f32x4*)(bp + oo0 + 4); \
        B[2] = *(const f32x4*)(bp + oo1); B[3] = *(const f32x4*)(bp + oo1 + 4); }

#define STEP_T(T, CUR, NXT) {                                                   \
        if (T < 5) LOAD_T(T + 1, NXT);                                          \
        bf16x8 ef0, ef1;                                                        \
        _Pragma("unroll")                                                       \
        for (int j = 0; j < 4; ++j) {                                           \
            ef0[j] = (__bf16)CUR[0][j]; ef0[j + 4] = (__bf16)CUR[1][j];         \
            ef1[j] = (__bf16)CUR[2][j]; ef1[j + 4] = (__bf16)CUR[3][j];         \
        }                                                                       \
        _Pragma("unroll")                                                       \
        for (int n = 0; n < 8; ++n) {                                           \
            bf16x8 w = *(const bf16x8*)(w1p + (n * 6 + T) * 512);               \
            acc1[0][n] = mfma32(w, ef0, acc1[0][n]);                            \
            acc1[1][n] = mfma32(w, ef1, acc1[1][n]);                            \
        }                                                                       \
        __builtin_amdgcn_sched_barrier(0); }

    while (c < nchunks) {
        const int base = c * 256 + wid * 32;

        // prefetch next chunk's indices under this chunk's compute
        const int cn = c + gridDim.x;
        int nis0 = 0, nid0 = 0, nis1 = 0, nid1 = 0, nie0 = 0, nie1 = 0;
        if (cn < nchunks) {
            int bb = cn * 256 + wid * 32;
            int e0 = bb + r16, e1 = bb + 16 + r16;
            nie0 = e0 < E ? e0 : E - 1;
            nie1 = e1 < E ? e1 : E - 1;
            nis0 = src_idx[nie0]; nid0 = dst_idx[nie0];
            nis1 = src_idx[nie1]; nid1 = dst_idx[nie1];
        }

        f32x4 acc1[2][8];
#pragma unroll
        for (int m = 0; m < 2; ++m)
#pragma unroll
            for (int n = 0; n < 8; ++n) acc1[m][n] = (f32x4){0.f, 0.f, 0.f, 0.f};

        // ---- GEMM1: double-buffered gather stream, paired 16-edge tiles ----
        f32x4 bufA[4], bufB[4];
        LOAD_T(0, bufA);
        STEP_T(0, bufA, bufB);
        STEP_T(1, bufB, bufA);
        STEP_T(2, bufA, bufB);
        STEP_T(3, bufB, bufA);
        STEP_T(4, bufA, bufB);
        STEP_T(5, bufB, bufA);

        // bias1 as one 16-wide K-step
#pragma unroll
        for (int n = 0; n < 8; ++n) {
            s16x4 wb = *(const s16x4*)(b1p + n * 256);
            acc1[0][n] = mfma16(wb, one, acc1[0][n]);
            acc1[1][n] = mfma16(wb, one, acc1[1][n]);
        }

        // ---- softplus + pack; acc1 dies here ----
        u32 P[2][8][2];
#pragma unroll
        for (int m = 0; m < 2; ++m)
#pragma unroll
            for (int n = 0; n < 8; ++n) {
                P[m][n][0] = packsp(acc1[m][n][0], acc1[m][n][1]);
                P[m][n][1] = packsp(acc1[m][n][2], acc1[m][n][3]);
            }

        // ---- GEMM2, rt-outer: only 2 accumulators live; store immediately ----
        const int e0 = base + r16, e1 = base + 16 + r16;
        float* op0 = out + (size_t)e0 * 64 + q * 4;
        float* op1 = out + (size_t)e1 * 64 + q * 4;
#pragma unroll
        for (int rt = 0; rt < 4; ++rt) {
            f32x4 a20 = {0.f, 0.f, 0.f, 0.f};
            f32x4 a21 = {0.f, 0.f, 0.f, 0.f};
#pragma unroll
            for (int np = 0; np < 4; ++np) {
                union { bf16x8 v8; s16x4 h[2]; } uw;
                uw.v8 = *(const bf16x8*)(w2p + (rt * 4 + np) * 512);
                a20 = mfma16(uw.h[0], mk4(P[0][2 * np][0],     P[0][2 * np][1]),     a20);
                a20 = mfma16(uw.h[1], mk4(P[0][2 * np + 1][0], P[0][2 * np + 1][1]), a20);
                a21 = mfma16(uw.h[0], mk4(P[1][2 * np][0],     P[1][2 * np][1]),     a21);
                a21 = mfma16(uw.h[1], mk4(P[1][2 * np + 1][0], P[1][2 * np + 1][1]), a21);
            }
            s16x4 wb2 = *(const s16x4*)(b2p + rt * 256);
            a20 = mfma16(wb2, one, a20);
            a21 = mfma16(wb2, one, a21);
            if (e0 < E) *(f32x4*)(op0 + rt * 16) = a20;
            if (e1 < E) *(f32x4*)(op1 + rt * 16) = a21;
        }

        // rotate prefetched indices into gather offsets
        if (cn < nchunks) {
            os0 = (u32)nis0 * 64 + ko; od0 = (u32)nid0 * 64 + ko;
            os1 = (u32)nis1 * 64 + ko; od1 = (u32)nid1 * 64 + ko;
            oe0 = (u32)nie0 * 64 + ko; oe1 = (u32)nie1 * 64 + ko;
        }
        c = cn;
    }
#undef LOAD_T
#undef STEP_T
}

extern "C" void kernel_launch(void* const* d_in, const int* in_sizes, int n_in,
                              void* d_out, int out_size, void* d_ws, size_t ws_size,
                              hipStream_t stream) {
    const float* node_feats = (const float*)d_in[0];
    const float* edge_feats = (const float*)d_in[1];
    const int*   src_idx    = (const int*)d_in[2];
    const int*   dst_idx    = (const int*)d_in[3];
    const float* W1         = (const float*)d_in[4];
    const float* b1         = (const float*)d_in[5];
    const float* W2         = (const float*)d_in[6];
    const float* b2         = (const float*)d_in[7];
    float* out = (float*)d_out;

    const int E = in_sizes[2];
    const int nchunks = (E + 255) / 256;
    int grid = nchunks < 512 ? nchunks : 512;

    edge_mlp_kernel<<<grid, 512, 0, stream>>>(node_feats, edge_feats, src_idx, dst_idx,
                                              W1, b1, W2, b2, out, E, nchunks);
}